// Round 1
// 326.455 us; speedup vs baseline: 1.0049x; 1.0049x over previous
//
#include <hip/hip_runtime.h>
#include <hip/hip_bf16.h>

// GCN layer: N=100000, E=1600000, IN=256, OUT=32, fp32.
// R8 was barrier-free gemm but grid-starved (391 blocks = 6 waves/CU) and
// VGPR-capped at 68 (no min-waves bound) so the compiler serialized the
// "16 float4 in flight" into drained batches -> 68us at 12% occupancy,
// 18% VALUBusy, 12% HBM.
// R9: gemm occupancy x ILP fix — G_ROWS=128 (782 blocks, all co-resident at
// 4 blocks/CU LDS cap => ~12 waves/CU), 4 rows x 4 cols per thread,
// explicit next-k-step prefetch, __launch_bounds__(256,4) so the prefetch
// registers exist (VGPR cap 128). W stays in LDS (32KB, conflict-free),
// degree-scale folded into epilogue, no k-loop barriers.
// Rest of the zero-global-atomic radix pipeline unchanged:
//   hist -> offset -> partition_src -> src_count -> gemm -> partition_dst
//   -> sort_agg (fused rsqrt+bias+relu).

#define IN_F 256
#define OUT_F 32

#define G_ROWS 128

// buckets / partition
#define BSHIFT 7
#define BNODES 128
#define NBK 1024
#define PB_EDGES 8192
#define AGG_CAP 4096

// ---------------- fast path ----------------

__global__ __launch_bounds__(1024) void hist_kernel(
    const int* __restrict__ src, const int* __restrict__ dst,
    unsigned short* __restrict__ mhistS, unsigned short* __restrict__ mhistD,
    int E) {
  __shared__ int hS[NBK], hD[NBK];
  int tid = threadIdx.x;
  hS[tid] = 0; hD[tid] = 0;
  __syncthreads();
  int e0 = blockIdx.x * PB_EDGES + tid * 8;
  if (e0 + 8 <= E) {
    int4 a0 = ((const int4*)(src + e0))[0], a1 = ((const int4*)(src + e0))[1];
    int4 b0 = ((const int4*)(dst + e0))[0], b1 = ((const int4*)(dst + e0))[1];
    int ss[8] = {a0.x, a0.y, a0.z, a0.w, a1.x, a1.y, a1.z, a1.w};
    int dd[8] = {b0.x, b0.y, b0.z, b0.w, b1.x, b1.y, b1.z, b1.w};
#pragma unroll
    for (int j = 0; j < 8; ++j) {
      atomicAdd(&hS[ss[j] >> BSHIFT], 1);
      atomicAdd(&hD[dd[j] >> BSHIFT], 1);
    }
  } else {
    for (int j = 0; j < 8; ++j) {
      int e = e0 + j * 1;
      if (e < E) {
        atomicAdd(&hS[src[e] >> BSHIFT], 1);
        atomicAdd(&hD[dst[e] >> BSHIFT], 1);
      }
    }
  }
  __syncthreads();
  mhistS[blockIdx.x * NBK + tid] = (unsigned short)hS[tid];
  mhistD[blockIdx.x * NBK + tid] = (unsigned short)hD[tid];
}

// blockIdx 0 -> S, 1 -> D. Converts mhist counts to within-bucket per-block
// exclusive prefixes and writes bucket base arrays.
__global__ __launch_bounds__(1024) void offset_kernel(
    unsigned short* __restrict__ mhistS, unsigned short* __restrict__ mhistD,
    int* __restrict__ baseS, int* __restrict__ baseD, int npb) {
  __shared__ int wsum[16];
  unsigned short* mh = blockIdx.x ? mhistD : mhistS;
  int* bb = blockIdx.x ? baseD : baseS;
  int b = threadIdx.x;
  int run = 0;
  for (int blk = 0; blk < npb; ++blk) {
    int idx = blk * NBK + b;
    int c = mh[idx];
    mh[idx] = (unsigned short)run;
    run += c;
  }
  int v = run, x = run;
#pragma unroll
  for (int d = 1; d < 64; d <<= 1) {
    int y = __shfl_up(x, d, 64);
    if ((b & 63) >= d) x += y;
  }
  if ((b & 63) == 63) wsum[b >> 6] = x;
  __syncthreads();
  int off = 0;
#pragma unroll
  for (int w = 0; w < 16; ++w)
    if (w < (b >> 6)) off += wsum[w];
  bb[b] = off + x - v;
  if (b == NBK - 1) bb[NBK] = off + x;
}

__global__ __launch_bounds__(1024) void partition_src_kernel(
    const int* __restrict__ src, const unsigned short* __restrict__ mbaseS,
    const int* __restrict__ baseS, unsigned char* __restrict__ pairs_s, int E) {
  __shared__ unsigned char sbuf[PB_EDGES];   // 8 KB
  __shared__ int hist[NBK];
  __shared__ int lbase[NBK + 1];
  __shared__ int gbase[NBK];
  __shared__ int wsum[16];

  int tid = threadIdx.x;
  hist[tid] = 0;
  __syncthreads();

  int e0 = blockIdx.x * PB_EDGES + tid * 8;
  int myb[8], myslot[8];
  unsigned char mylow[8];
  if (e0 + 8 <= E) {
    int4 a0 = ((const int4*)(src + e0))[0], a1 = ((const int4*)(src + e0))[1];
    int ss[8] = {a0.x, a0.y, a0.z, a0.w, a1.x, a1.y, a1.z, a1.w};
#pragma unroll
    for (int j = 0; j < 8; ++j) {
      int b = ss[j] >> BSHIFT;
      myb[j] = b;
      mylow[j] = (unsigned char)(ss[j] & (BNODES - 1));
      myslot[j] = atomicAdd(&hist[b], 1);
    }
  } else {
#pragma unroll
    for (int j = 0; j < 8; ++j) {
      int e = e0 + j;
      if (e < E) {
        int s = src[e];
        int b = s >> BSHIFT;
        myb[j] = b;
        mylow[j] = (unsigned char)(s & (BNODES - 1));
        myslot[j] = atomicAdd(&hist[b], 1);
      } else {
        myb[j] = -1;
      }
    }
  }
  __syncthreads();

  {
    int v = hist[tid];
    int x = v;
#pragma unroll
    for (int d = 1; d < 64; d <<= 1) {
      int y = __shfl_up(x, d, 64);
      if ((tid & 63) >= d) x += y;
    }
    if ((tid & 63) == 63) wsum[tid >> 6] = x;
    __syncthreads();
    int off = 0;
#pragma unroll
    for (int w = 0; w < 16; ++w)
      if (w < (tid >> 6)) off += wsum[w];
    lbase[tid] = off + x - v;
    if (tid == NBK - 1) lbase[NBK] = off + x;
    gbase[tid] = baseS[tid] + (int)mbaseS[blockIdx.x * NBK + tid];
  }
  __syncthreads();

#pragma unroll
  for (int j = 0; j < 8; ++j)
    if (myb[j] >= 0) sbuf[lbase[myb[j]] + myslot[j]] = mylow[j];
  __syncthreads();

  int total = lbase[NBK];
  int idx = tid * 8;
  if (idx < total) {
    int lo = 0, hi = NBK;
    while (hi - lo > 1) {
      int mid = (lo + hi) >> 1;
      if (lbase[mid] <= idx) lo = mid; else hi = mid;
    }
    int b = lo;
#pragma unroll
    for (int j = 0; j < 8; ++j, ++idx) {
      if (idx >= total) break;
      while (idx >= lbase[b + 1]) ++b;
      pairs_s[gbase[b] + (idx - lbase[b])] = sbuf[idx];
    }
  }
}

__global__ __launch_bounds__(256) void src_count_kernel(
    const unsigned char* __restrict__ pairs_s, const int* __restrict__ baseS,
    float* __restrict__ scale_out, int N) {
  __shared__ int hist[BNODES];
  int tid = threadIdx.x;
  int b = blockIdx.x;
  if (tid < BNODES) hist[tid] = 0;
  __syncthreads();
  int s = baseS[b], e = baseS[b + 1];
  for (int i = s + tid; i < e; i += 256) atomicAdd(&hist[pairs_s[i]], 1);
  __syncthreads();
  if (tid < BNODES) {
    int node = (b << BSHIFT) + tid;
    if (node < N) {
      int c = hist[tid];
      scale_out[node] = (c < 1) ? 1.f : rsqrtf((float)c);
    }
  }
}

// h[n][o] = scale_out[n] * sum_k feat[n][k] * W[k][o]
// Barrier-free: thread owns 4 rows (stride 32) x 4 cols; feat streamed
// directly from global (float4), next k-step prefetched while current
// computes; W resident in LDS. launch_bounds(256,4) => VGPR cap 128 so the
// prefetch actually stays in flight (R8's 68-VGPR cap serialized it).
__global__ __launch_bounds__(256, 4) void gemm_kernel(
    const float* __restrict__ feat, const float* __restrict__ W,
    const float* __restrict__ scale_out, float* __restrict__ h, int N) {
  __shared__ float sW[IN_F * OUT_F];   // [k][o], 32 KB
  __shared__ float sScale[G_ROWS];

  int tid = threadIdx.x;
  {
    const float4* W4 = (const float4*)W;
    float4* sW4 = (float4*)sW;
#pragma unroll
    for (int i = 0; i < 8; ++i) sW4[tid + i * 256] = W4[tid + i * 256];
  }
  int row0 = blockIdx.x * G_ROWS;
  if (tid < G_ROWS) {
    int gr = row0 + tid;
    sScale[tid] = (gr < N) ? scale_out[gr] : 0.f;
  }
  __syncthreads();

  int tr = tid >> 3;          // 0..31
  int cg = (tid & 7) * 4;     // col group
  const float* fp[4];
  bool valid[4];
#pragma unroll
  for (int i = 0; i < 4; ++i) {
    int g = row0 + tr + 32 * i;
    valid[i] = (g < N);
    fp[i] = feat + (size_t)(valid[i] ? g : 0) * IN_F;
  }

  float acc[4][4];
#pragma unroll
  for (int i = 0; i < 4; ++i)
#pragma unroll
    for (int c = 0; c < 4; ++c) acc[i][c] = 0.f;

  // current k-step (k..k+7) registers, prefetched
  float4 ca[4], cb[4];
#pragma unroll
  for (int i = 0; i < 4; ++i) ca[i] = *(const float4*)(fp[i] + 0);
#pragma unroll
  for (int i = 0; i < 4; ++i) cb[i] = *(const float4*)(fp[i] + 4);

  auto step = [&](int k, const float4* A0, const float4* A1) {
#pragma unroll
    for (int j = 0; j < 4; ++j) {
      float4 w = *(const float4*)(sW + (k + j) * OUT_F + cg);
#pragma unroll
      for (int i = 0; i < 4; ++i) {
        float aj = (j == 0) ? A0[i].x : (j == 1) ? A0[i].y : (j == 2) ? A0[i].z : A0[i].w;
        acc[i][0] = fmaf(aj, w.x, acc[i][0]);
        acc[i][1] = fmaf(aj, w.y, acc[i][1]);
        acc[i][2] = fmaf(aj, w.z, acc[i][2]);
        acc[i][3] = fmaf(aj, w.w, acc[i][3]);
      }
    }
#pragma unroll
    for (int j = 0; j < 4; ++j) {
      float4 w = *(const float4*)(sW + (k + 4 + j) * OUT_F + cg);
#pragma unroll
      for (int i = 0; i < 4; ++i) {
        float aj = (j == 0) ? A1[i].x : (j == 1) ? A1[i].y : (j == 2) ? A1[i].z : A1[i].w;
        acc[i][0] = fmaf(aj, w.x, acc[i][0]);
        acc[i][1] = fmaf(aj, w.y, acc[i][1]);
        acc[i][2] = fmaf(aj, w.z, acc[i][2]);
        acc[i][3] = fmaf(aj, w.w, acc[i][3]);
      }
    }
  };

  for (int k = 0; k < IN_F - 8; k += 8) {
    float4 na[4], nb[4];
#pragma unroll
    for (int i = 0; i < 4; ++i) na[i] = *(const float4*)(fp[i] + k + 8);
#pragma unroll
    for (int i = 0; i < 4; ++i) nb[i] = *(const float4*)(fp[i] + k + 12);
    step(k, ca, cb);
#pragma unroll
    for (int i = 0; i < 4; ++i) { ca[i] = na[i]; cb[i] = nb[i]; }
  }
  step(IN_F - 8, ca, cb);

#pragma unroll
  for (int i = 0; i < 4; ++i) {
    int r = tr + 32 * i;
    if (valid[i]) {
      float s = sScale[r];
      float4 o = {acc[i][0] * s, acc[i][1] * s, acc[i][2] * s, acc[i][3] * s};
      *(float4*)(h + (size_t)(row0 + r) * OUT_F + cg) = o;
    }
  }
}

__global__ __launch_bounds__(1024) void partition_dst_kernel(
    const int* __restrict__ src, const int* __restrict__ dst,
    const unsigned short* __restrict__ mbaseD, const int* __restrict__ baseD,
    unsigned* __restrict__ pairs, int E) {
  __shared__ unsigned sbuf[PB_EDGES];   // 32 KB
  __shared__ int hist[NBK];
  __shared__ int lbase[NBK + 1];
  __shared__ int gbase[NBK];
  __shared__ int wsum[16];

  int tid = threadIdx.x;
  hist[tid] = 0;
  __syncthreads();

  int e0 = blockIdx.x * PB_EDGES + tid * 8;
  int myb[8], myslot[8];
  unsigned mypk[8];
  if (e0 + 8 <= E) {
    int4 a0 = ((const int4*)(src + e0))[0], a1 = ((const int4*)(src + e0))[1];
    int4 b0 = ((const int4*)(dst + e0))[0], b1 = ((const int4*)(dst + e0))[1];
    int ss[8] = {a0.x, a0.y, a0.z, a0.w, a1.x, a1.y, a1.z, a1.w};
    int dd[8] = {b0.x, b0.y, b0.z, b0.w, b1.x, b1.y, b1.z, b1.w};
#pragma unroll
    for (int j = 0; j < 8; ++j) {
      int b = dd[j] >> BSHIFT;
      myb[j] = b;
      mypk[j] = (unsigned)ss[j] | ((unsigned)(dd[j] & (BNODES - 1)) << 17);
      myslot[j] = atomicAdd(&hist[b], 1);
    }
  } else {
#pragma unroll
    for (int j = 0; j < 8; ++j) {
      int e = e0 + j;
      if (e < E) {
        int s = src[e], d = dst[e];
        int b = d >> BSHIFT;
        myb[j] = b;
        mypk[j] = (unsigned)s | ((unsigned)(d & (BNODES - 1)) << 17);
        myslot[j] = atomicAdd(&hist[b], 1);
      } else {
        myb[j] = -1;
      }
    }
  }
  __syncthreads();

  {
    int v = hist[tid];
    int x = v;
#pragma unroll
    for (int d = 1; d < 64; d <<= 1) {
      int y = __shfl_up(x, d, 64);
      if ((tid & 63) >= d) x += y;
    }
    if ((tid & 63) == 63) wsum[tid >> 6] = x;
    __syncthreads();
    int off = 0;
#pragma unroll
    for (int w = 0; w < 16; ++w)
      if (w < (tid >> 6)) off += wsum[w];
    lbase[tid] = off + x - v;
    if (tid == NBK - 1) lbase[NBK] = off + x;
    gbase[tid] = baseD[tid] + (int)mbaseD[blockIdx.x * NBK + tid];
  }
  __syncthreads();

#pragma unroll
  for (int j = 0; j < 8; ++j)
    if (myb[j] >= 0) sbuf[lbase[myb[j]] + myslot[j]] = mypk[j];
  __syncthreads();

  int total = lbase[NBK];
  int idx = tid * 8;
  if (idx < total) {
    int lo = 0, hi = NBK;
    while (hi - lo > 1) {
      int mid = (lo + hi) >> 1;
      if (lbase[mid] <= idx) lo = mid; else hi = mid;
    }
    int b = lo;
#pragma unroll
    for (int j = 0; j < 8; ++j, ++idx) {
      if (idx >= total) break;
      while (idx >= lbase[b + 1]) ++b;
      pairs[gbase[b] + (idx - lbase[b])] = sbuf[idx];
    }
  }
}

// Per 128-node dst bucket: counting-sort by dstlow, register-accumulate runs.
__global__ __launch_bounds__(256) void sort_agg_kernel(
    const unsigned* __restrict__ pairs, const int* __restrict__ baseD,
    const float* __restrict__ h, const float* __restrict__ bias,
    float* __restrict__ out, int N) {
  __shared__ unsigned spk[AGG_CAP];   // 16 KB
  __shared__ int hist[BNODES];
  __shared__ int rs[BNODES + 1];
  __shared__ int wsum2[4];

  int tid = threadIdx.x;
  int lane = tid & 31;
  int eg = tid >> 5;
  int b = blockIdx.x;
  int start = baseD[b];
  int end = baseD[b + 1];

  float acc[16];
  int degc[16];
#pragma unroll
  for (int t = 0; t < 16; ++t) { acc[t] = 0.f; degc[t] = 0; }

  for (int chunk = start; chunk < end; chunk += AGG_CAP) {
    int cnt = min(end - chunk, AGG_CAP);
    if (tid < BNODES) hist[tid] = 0;
    __syncthreads();

    unsigned mypk[16];
    int myslot[16];
    int nmine = 0;
    for (int i = tid; i < cnt; i += 256) {
      unsigned pk = pairs[chunk + i];
      mypk[nmine] = pk;
      myslot[nmine] = atomicAdd(&hist[pk >> 17], 1);
      ++nmine;
    }
    __syncthreads();

    {
      int v = (tid < BNODES) ? hist[tid] : 0;
      int x = v;
#pragma unroll
      for (int d = 1; d < 64; d <<= 1) {
        int y = __shfl_up(x, d, 64);
        if ((tid & 63) >= d) x += y;
      }
      if ((tid & 63) == 63) wsum2[tid >> 6] = x;
      __syncthreads();
      int off = (tid >= 64 && tid < BNODES) ? wsum2[0] : 0;
      if (tid < BNODES) rs[tid] = off + x - v;
      if (tid == BNODES - 1) rs[BNODES] = off + x;
    }
    __syncthreads();

    for (int i = 0; i < nmine; ++i) {
      unsigned pk = mypk[i];
      spk[rs[pk >> 17] + myslot[i]] = pk;
    }
    __syncthreads();

#pragma unroll 1
    for (int t = 0; t < 16; ++t) {
      int n = eg * 16 + t;
      int a = rs[n], bnd = rs[n + 1];
      degc[t] += bnd - a;
      float s = acc[t];
      int j = a;
      for (; j + 4 <= bnd; j += 4) {
        unsigned p0 = spk[j], p1 = spk[j + 1], p2 = spk[j + 2], p3 = spk[j + 3];
        float f0 = h[(size_t)(p0 & 0x1FFFF) * OUT_F + lane];
        float f1 = h[(size_t)(p1 & 0x1FFFF) * OUT_F + lane];
        float f2 = h[(size_t)(p2 & 0x1FFFF) * OUT_F + lane];
        float f3 = h[(size_t)(p3 & 0x1FFFF) * OUT_F + lane];
        s += f0; s += f1; s += f2; s += f3;
      }
      for (; j < bnd; ++j)
        s += h[(size_t)(spk[j] & 0x1FFFF) * OUT_F + lane];
      acc[t] = s;
    }
    __syncthreads();
  }

  int node0 = b << BSHIFT;
#pragma unroll
  for (int t = 0; t < 16; ++t) {
    int node = node0 + eg * 16 + t;
    if (node < N) {
      float sc = degc[t] > 0 ? rsqrtf((float)degc[t]) : 1.f;
      out[(size_t)node * OUT_F + lane] = fmaxf(fmaf(acc[t], sc, bias[lane]), 0.f);
    }
  }
}

// ---------------- fallback (float-atomic) path ----------------
__global__ __launch_bounds__(256) void degree_kernel(
    const int* __restrict__ src, const int* __restrict__ dst,
    int* __restrict__ cnt_out, int* __restrict__ cnt_in, int E) {
  int i = blockIdx.x * 256 + threadIdx.x;
  if (i < E) {
    atomicAdd(cnt_out + src[i], 1);
    atomicAdd(cnt_in + dst[i], 1);
  }
}

__global__ __launch_bounds__(256) void cnt_to_scale_kernel(
    const int* __restrict__ cnt, float* __restrict__ scale, int N) {
  int i = blockIdx.x * 256 + threadIdx.x;
  if (i < N) {
    int c = cnt[i];
    scale[i] = (c < 1) ? 1.f : rsqrtf((float)c);
  }
}

__global__ __launch_bounds__(256) void aggregate_kernel(
    const int* __restrict__ src, const int* __restrict__ dst,
    const float* __restrict__ h, float* __restrict__ out, int E) {
  int lane = threadIdx.x & 31;
  int e = (blockIdx.x * 256 + threadIdx.x) >> 5;
  if (e >= E) return;
  float v = h[(size_t)src[e] * OUT_F + lane];
  unsafeAtomicAdd(out + (size_t)dst[e] * OUT_F + lane, v);
}

__global__ __launch_bounds__(256) void finalize_kernel(
    float* __restrict__ out, const int* __restrict__ cnt_in,
    const float* __restrict__ bias, int N) {
  int idx = blockIdx.x * 256 + threadIdx.x;
  if (idx >= N * 8) return;
  int n = idx >> 3;
  int o = (idx & 7) * 4;
  float dg = (float)cnt_in[n];
  float s = dg < 1.f ? 1.f : rsqrtf(dg);
  float4 bv = *(const float4*)(bias + o);
  float4 v = ((const float4*)out)[idx];
  v.x = fmaxf(fmaf(v.x, s, bv.x), 0.f);
  v.y = fmaxf(fmaf(v.y, s, bv.y), 0.f);
  v.z = fmaxf(fmaf(v.z, s, bv.z), 0.f);
  v.w = fmaxf(fmaf(v.w, s, bv.w), 0.f);
  ((float4*)out)[idx] = v;
}

extern "C" void kernel_launch(void* const* d_in, const int* in_sizes, int n_in,
                              void* d_out, int out_size, void* d_ws, size_t ws_size,
                              hipStream_t stream) {
  const float* feat = (const float*)d_in[0];
  const int* src = (const int*)d_in[1];
  const int* dst = (const int*)d_in[2];
  const float* weight = (const float*)d_in[3];
  const float* bias = (const float*)d_in[4];
  float* out = (float*)d_out;

  int N = in_sizes[0] / IN_F;
  int E = in_sizes[1];
  int nb = (N + BNODES - 1) >> BSHIFT;
  int npb = (E + PB_EDGES - 1) / PB_EDGES;

  float* h = (float*)d_ws;                                   // N*32 f32
  unsigned* pairs = (unsigned*)(h + (size_t)N * OUT_F);      // E u32
  unsigned char* pairs_s = (unsigned char*)pairs;
  unsigned short* mhistS = (unsigned short*)(pairs + E);     // npb*NBK u16
  unsigned short* mhistD = mhistS + (size_t)npb * NBK;       // npb*NBK u16
  int* baseS = (int*)(mhistD + (size_t)npb * NBK);           // NBK+1
  int* baseD = baseS + NBK + 1;                              // NBK+1
  float* scale_out = (float*)(baseD + NBK + 1);              // N f32

  size_t need = ((size_t)N * OUT_F + (size_t)E + (size_t)N + 2 * (NBK + 1)) * 4 +
                (size_t)npb * NBK * 2 * 2;
  bool fast = (ws_size >= need) && (N <= (1 << 17)) && (nb <= NBK);

  if (fast) {
    hist_kernel<<<npb, 1024, 0, stream>>>(src, dst, mhistS, mhistD, E);
    offset_kernel<<<2, 1024, 0, stream>>>(mhistS, mhistD, baseS, baseD, npb);
    partition_src_kernel<<<npb, 1024, 0, stream>>>(src, mhistS, baseS, pairs_s, E);
    src_count_kernel<<<nb, 256, 0, stream>>>(pairs_s, baseS, scale_out, N);
    gemm_kernel<<<(N + G_ROWS - 1) / G_ROWS, 256, 0, stream>>>(
        feat, weight, scale_out, h, N);
    partition_dst_kernel<<<npb, 1024, 0, stream>>>(src, dst, mhistD, baseD, pairs, E);
    sort_agg_kernel<<<nb, 256, 0, stream>>>(pairs, baseD, h, bias, out, N);
  } else {
    int* cnt_out = (int*)(h + (size_t)N * OUT_F);
    int* cnt_in = cnt_out + N;
    float* scl = (float*)(cnt_in + N);
    hipMemsetAsync(cnt_out, 0, (size_t)2 * N * sizeof(int), stream);
    hipMemsetAsync(out, 0, (size_t)N * OUT_F * sizeof(float), stream);
    degree_kernel<<<(E + 255) / 256, 256, 0, stream>>>(src, dst, cnt_out, cnt_in, E);
    cnt_to_scale_kernel<<<(N + 255) / 256, 256, 0, stream>>>(cnt_out, scl, N);
    gemm_kernel<<<(N + G_ROWS - 1) / G_ROWS, 256, 0, stream>>>(feat, weight, scl, h, N);
    aggregate_kernel<<<(E + 7) / 8, 256, 0, stream>>>(src, dst, h, out, E);
    finalize_kernel<<<(N * 8 + 255) / 256, 256, 0, stream>>>(out, cnt_in, bias, N);
  }
}

// Round 2
// 318.365 us; speedup vs baseline: 1.0305x; 1.0254x over previous
//
#include <hip/hip_runtime.h>
#include <hip/hip_bf16.h>

// GCN layer: N=100000, E=1600000, IN=256, OUT=32, fp32.
// R9 post-mortem: compiler capped gemm at 64 VGPR regardless of
// launch_bounds and serialized the register prefetch (68us, 5100cy/k-step
// = 8 loads x ~600cy serial). R10: take VGPRs out of the streaming path —
// feat staged into LDS via __builtin_amdgcn_global_load_lds (width=16,
// DMA, no VGPR round-trip), double-buffered 128x16 tiles, XOR-swizzled
// GLOBAL source so LDS stays DMA-linear while ds_read_b128 is <=2-way
// conflict-free. 48.7KB LDS -> 3 blocks/CU = 12 waves/CU (grid 782 = 3.05
// blocks/CU, fully co-resident). stage(next) -> compute(cur) -> barrier:
// vmcnt drain overlaps compute.
// Rest of the zero-global-atomic radix pipeline unchanged:
//   hist -> offset -> partition_src -> src_count -> gemm -> partition_dst
//   -> sort_agg (fused rsqrt+bias+relu).

#define IN_F 256
#define OUT_F 32

#define G_ROWS 128
#define G_BK 16

// buckets / partition
#define BSHIFT 7
#define BNODES 128
#define NBK 1024
#define PB_EDGES 8192
#define AGG_CAP 4096

// ---------------- fast path ----------------

__global__ __launch_bounds__(1024) void hist_kernel(
    const int* __restrict__ src, const int* __restrict__ dst,
    unsigned short* __restrict__ mhistS, unsigned short* __restrict__ mhistD,
    int E) {
  __shared__ int hS[NBK], hD[NBK];
  int tid = threadIdx.x;
  hS[tid] = 0; hD[tid] = 0;
  __syncthreads();
  int e0 = blockIdx.x * PB_EDGES + tid * 8;
  if (e0 + 8 <= E) {
    int4 a0 = ((const int4*)(src + e0))[0], a1 = ((const int4*)(src + e0))[1];
    int4 b0 = ((const int4*)(dst + e0))[0], b1 = ((const int4*)(dst + e0))[1];
    int ss[8] = {a0.x, a0.y, a0.z, a0.w, a1.x, a1.y, a1.z, a1.w};
    int dd[8] = {b0.x, b0.y, b0.z, b0.w, b1.x, b1.y, b1.z, b1.w};
#pragma unroll
    for (int j = 0; j < 8; ++j) {
      atomicAdd(&hS[ss[j] >> BSHIFT], 1);
      atomicAdd(&hD[dd[j] >> BSHIFT], 1);
    }
  } else {
    for (int j = 0; j < 8; ++j) {
      int e = e0 + j * 1;
      if (e < E) {
        atomicAdd(&hS[src[e] >> BSHIFT], 1);
        atomicAdd(&hD[dst[e] >> BSHIFT], 1);
      }
    }
  }
  __syncthreads();
  mhistS[blockIdx.x * NBK + tid] = (unsigned short)hS[tid];
  mhistD[blockIdx.x * NBK + tid] = (unsigned short)hD[tid];
}

// blockIdx 0 -> S, 1 -> D. Converts mhist counts to within-bucket per-block
// exclusive prefixes and writes bucket base arrays.
__global__ __launch_bounds__(1024) void offset_kernel(
    unsigned short* __restrict__ mhistS, unsigned short* __restrict__ mhistD,
    int* __restrict__ baseS, int* __restrict__ baseD, int npb) {
  __shared__ int wsum[16];
  unsigned short* mh = blockIdx.x ? mhistD : mhistS;
  int* bb = blockIdx.x ? baseD : baseS;
  int b = threadIdx.x;
  int run = 0;
  for (int blk = 0; blk < npb; ++blk) {
    int idx = blk * NBK + b;
    int c = mh[idx];
    mh[idx] = (unsigned short)run;
    run += c;
  }
  int v = run, x = run;
#pragma unroll
  for (int d = 1; d < 64; d <<= 1) {
    int y = __shfl_up(x, d, 64);
    if ((b & 63) >= d) x += y;
  }
  if ((b & 63) == 63) wsum[b >> 6] = x;
  __syncthreads();
  int off = 0;
#pragma unroll
  for (int w = 0; w < 16; ++w)
    if (w < (b >> 6)) off += wsum[w];
  bb[b] = off + x - v;
  if (b == NBK - 1) bb[NBK] = off + x;
}

__global__ __launch_bounds__(1024) void partition_src_kernel(
    const int* __restrict__ src, const unsigned short* __restrict__ mbaseS,
    const int* __restrict__ baseS, unsigned char* __restrict__ pairs_s, int E) {
  __shared__ unsigned char sbuf[PB_EDGES];   // 8 KB
  __shared__ int hist[NBK];
  __shared__ int lbase[NBK + 1];
  __shared__ int gbase[NBK];
  __shared__ int wsum[16];

  int tid = threadIdx.x;
  hist[tid] = 0;
  __syncthreads();

  int e0 = blockIdx.x * PB_EDGES + tid * 8;
  int myb[8], myslot[8];
  unsigned char mylow[8];
  if (e0 + 8 <= E) {
    int4 a0 = ((const int4*)(src + e0))[0], a1 = ((const int4*)(src + e0))[1];
    int ss[8] = {a0.x, a0.y, a0.z, a0.w, a1.x, a1.y, a1.z, a1.w};
#pragma unroll
    for (int j = 0; j < 8; ++j) {
      int b = ss[j] >> BSHIFT;
      myb[j] = b;
      mylow[j] = (unsigned char)(ss[j] & (BNODES - 1));
      myslot[j] = atomicAdd(&hist[b], 1);
    }
  } else {
#pragma unroll
    for (int j = 0; j < 8; ++j) {
      int e = e0 + j;
      if (e < E) {
        int s = src[e];
        int b = s >> BSHIFT;
        myb[j] = b;
        mylow[j] = (unsigned char)(s & (BNODES - 1));
        myslot[j] = atomicAdd(&hist[b], 1);
      } else {
        myb[j] = -1;
      }
    }
  }
  __syncthreads();

  {
    int v = hist[tid];
    int x = v;
#pragma unroll
    for (int d = 1; d < 64; d <<= 1) {
      int y = __shfl_up(x, d, 64);
      if ((tid & 63) >= d) x += y;
    }
    if ((tid & 63) == 63) wsum[tid >> 6] = x;
    __syncthreads();
    int off = 0;
#pragma unroll
    for (int w = 0; w < 16; ++w)
      if (w < (tid >> 6)) off += wsum[w];
    lbase[tid] = off + x - v;
    if (tid == NBK - 1) lbase[NBK] = off + x;
    gbase[tid] = baseS[tid] + (int)mbaseS[blockIdx.x * NBK + tid];
  }
  __syncthreads();

#pragma unroll
  for (int j = 0; j < 8; ++j)
    if (myb[j] >= 0) sbuf[lbase[myb[j]] + myslot[j]] = mylow[j];
  __syncthreads();

  int total = lbase[NBK];
  int idx = tid * 8;
  if (idx < total) {
    int lo = 0, hi = NBK;
    while (hi - lo > 1) {
      int mid = (lo + hi) >> 1;
      if (lbase[mid] <= idx) lo = mid; else hi = mid;
    }
    int b = lo;
#pragma unroll
    for (int j = 0; j < 8; ++j, ++idx) {
      if (idx >= total) break;
      while (idx >= lbase[b + 1]) ++b;
      pairs_s[gbase[b] + (idx - lbase[b])] = sbuf[idx];
    }
  }
}

__global__ __launch_bounds__(256) void src_count_kernel(
    const unsigned char* __restrict__ pairs_s, const int* __restrict__ baseS,
    float* __restrict__ scale_out, int N) {
  __shared__ int hist[BNODES];
  int tid = threadIdx.x;
  int b = blockIdx.x;
  if (tid < BNODES) hist[tid] = 0;
  __syncthreads();
  int s = baseS[b], e = baseS[b + 1];
  for (int i = s + tid; i < e; i += 256) atomicAdd(&hist[pairs_s[i]], 1);
  __syncthreads();
  if (tid < BNODES) {
    int node = (b << BSHIFT) + tid;
    if (node < N) {
      int c = hist[tid];
      scale_out[node] = (c < 1) ? 1.f : rsqrtf((float)c);
    }
  }
}

// Stage one 128x16 feat tile into LDS via global_load_lds (16B DMA).
// LDS dest is lane-linear (chunk p = q*256+tid); the k-chunk swizzle
// (p&3)^(row&3) is applied on the GLOBAL source address so the read side
// (ds_read_b128 at chunk (r<<2)|(c^(r&3))) is <=2-way bank-aliased (free).
__device__ __forceinline__ void stage_tile(
    const float* __restrict__ feat, float* sf, int row0, int k0, int N,
    int tid) {
#pragma unroll
  for (int q = 0; q < 2; ++q) {
    int p = q * 256 + tid;
    int row = p >> 2;
    int c = (p & 3) ^ (row & 3);
    int g = row0 + row;
    if (g >= N) g = N - 1;
    const float* gp = feat + (size_t)g * IN_F + k0 + c * 4;
    __builtin_amdgcn_global_load_lds(
        (const __attribute__((address_space(1))) unsigned int*)gp,
        (__attribute__((address_space(3))) unsigned int*)(sf + p * 4),
        16, 0, 0);
  }
}

// h[n][o] = scale_out[n] * sum_k feat[n][k] * W[k][o]
// Thread owns 4 rows (stride 32) x 4 cols. feat double-buffered in LDS via
// global_load_lds; W resident in LDS (broadcast reads, conflict-free).
// Per tile: stage(next) -> compute(cur) -> barrier (vmcnt drain overlaps
// compute). 48.7KB LDS -> 3 blocks/CU.
__global__ __launch_bounds__(256, 3) void gemm_kernel(
    const float* __restrict__ feat, const float* __restrict__ W,
    const float* __restrict__ scale_out, float* __restrict__ h, int N) {
  __shared__ float sW[IN_F * OUT_F];          // [k][o], 32 KB
  __shared__ float sF[2][G_ROWS * G_BK];      // 2 x 8 KB
  __shared__ float sScale[G_ROWS];

  int tid = threadIdx.x;
  {
    const float4* W4 = (const float4*)W;
    float4* sW4 = (float4*)sW;
#pragma unroll
    for (int i = 0; i < 8; ++i) sW4[tid + i * 256] = W4[tid + i * 256];
  }
  int row0 = blockIdx.x * G_ROWS;
  if (tid < G_ROWS) {
    int gr = row0 + tid;
    sScale[tid] = (gr < N) ? scale_out[gr] : 0.f;
  }

  stage_tile(feat, &sF[0][0], row0, 0, N, tid);

  int tr = tid >> 3;          // 0..31
  int cg = (tid & 7) * 4;     // col group

  float acc[4][4];
#pragma unroll
  for (int i = 0; i < 4; ++i)
#pragma unroll
    for (int c = 0; c < 4; ++c) acc[i][c] = 0.f;

  __syncthreads();            // tile 0 landed (vmcnt drained), sW ready

  const int NT = IN_F / G_BK;  // 16 tiles
  for (int t = 0; t < NT; ++t) {
    if (t + 1 < NT)
      stage_tile(feat, &sF[(t + 1) & 1][0], row0, (t + 1) * G_BK, N, tid);

    const float* sf = &sF[t & 1][0];
    int kb = t * G_BK;
#pragma unroll
    for (int c = 0; c < 4; ++c) {
      float4 a[4];
#pragma unroll
      for (int i = 0; i < 4; ++i) {
        int r = tr + 32 * i;
        int chunk = (r << 2) | (c ^ (r & 3));
        a[i] = *(const float4*)(sf + chunk * 4);
      }
#pragma unroll
      for (int j = 0; j < 4; ++j) {
        float4 w = *(const float4*)(sW + (kb + c * 4 + j) * OUT_F + cg);
#pragma unroll
        for (int i = 0; i < 4; ++i) {
          float aj = (j == 0) ? a[i].x : (j == 1) ? a[i].y
                   : (j == 2) ? a[i].z : a[i].w;
          acc[i][0] = fmaf(aj, w.x, acc[i][0]);
          acc[i][1] = fmaf(aj, w.y, acc[i][1]);
          acc[i][2] = fmaf(aj, w.z, acc[i][2]);
          acc[i][3] = fmaf(aj, w.w, acc[i][3]);
        }
      }
    }
    __syncthreads();          // next tile landed; cur buffer free
  }

#pragma unroll
  for (int i = 0; i < 4; ++i) {
    int r = tr + 32 * i;
    int g = row0 + r;
    if (g < N) {
      float s = sScale[r];
      float4 o = {acc[i][0] * s, acc[i][1] * s, acc[i][2] * s, acc[i][3] * s};
      *(float4*)(h + (size_t)g * OUT_F + cg) = o;
    }
  }
}

__global__ __launch_bounds__(1024) void partition_dst_kernel(
    const int* __restrict__ src, const int* __restrict__ dst,
    const unsigned short* __restrict__ mbaseD, const int* __restrict__ baseD,
    unsigned* __restrict__ pairs, int E) {
  __shared__ unsigned sbuf[PB_EDGES];   // 32 KB
  __shared__ int hist[NBK];
  __shared__ int lbase[NBK + 1];
  __shared__ int gbase[NBK];
  __shared__ int wsum[16];

  int tid = threadIdx.x;
  hist[tid] = 0;
  __syncthreads();

  int e0 = blockIdx.x * PB_EDGES + tid * 8;
  int myb[8], myslot[8];
  unsigned mypk[8];
  if (e0 + 8 <= E) {
    int4 a0 = ((const int4*)(src + e0))[0], a1 = ((const int4*)(src + e0))[1];
    int4 b0 = ((const int4*)(dst + e0))[0], b1 = ((const int4*)(dst + e0))[1];
    int ss[8] = {a0.x, a0.y, a0.z, a0.w, a1.x, a1.y, a1.z, a1.w};
    int dd[8] = {b0.x, b0.y, b0.z, b0.w, b1.x, b1.y, b1.z, b1.w};
#pragma unroll
    for (int j = 0; j < 8; ++j) {
      int b = dd[j] >> BSHIFT;
      myb[j] = b;
      mypk[j] = (unsigned)ss[j] | ((unsigned)(dd[j] & (BNODES - 1)) << 17);
      myslot[j] = atomicAdd(&hist[b], 1);
    }
  } else {
#pragma unroll
    for (int j = 0; j < 8; ++j) {
      int e = e0 + j;
      if (e < E) {
        int s = src[e], d = dst[e];
        int b = d >> BSHIFT;
        myb[j] = b;
        mypk[j] = (unsigned)s | ((unsigned)(d & (BNODES - 1)) << 17);
        myslot[j] = atomicAdd(&hist[b], 1);
      } else {
        myb[j] = -1;
      }
    }
  }
  __syncthreads();

  {
    int v = hist[tid];
    int x = v;
#pragma unroll
    for (int d = 1; d < 64; d <<= 1) {
      int y = __shfl_up(x, d, 64);
      if ((tid & 63) >= d) x += y;
    }
    if ((tid & 63) == 63) wsum[tid >> 6] = x;
    __syncthreads();
    int off = 0;
#pragma unroll
    for (int w = 0; w < 16; ++w)
      if (w < (tid >> 6)) off += wsum[w];
    lbase[tid] = off + x - v;
    if (tid == NBK - 1) lbase[NBK] = off + x;
    gbase[tid] = baseD[tid] + (int)mbaseD[blockIdx.x * NBK + tid];
  }
  __syncthreads();

#pragma unroll
  for (int j = 0; j < 8; ++j)
    if (myb[j] >= 0) sbuf[lbase[myb[j]] + myslot[j]] = mypk[j];
  __syncthreads();

  int total = lbase[NBK];
  int idx = tid * 8;
  if (idx < total) {
    int lo = 0, hi = NBK;
    while (hi - lo > 1) {
      int mid = (lo + hi) >> 1;
      if (lbase[mid] <= idx) lo = mid; else hi = mid;
    }
    int b = lo;
#pragma unroll
    for (int j = 0; j < 8; ++j, ++idx) {
      if (idx >= total) break;
      while (idx >= lbase[b + 1]) ++b;
      pairs[gbase[b] + (idx - lbase[b])] = sbuf[idx];
    }
  }
}

// Per 128-node dst bucket: counting-sort by dstlow, register-accumulate runs.
__global__ __launch_bounds__(256) void sort_agg_kernel(
    const unsigned* __restrict__ pairs, const int* __restrict__ baseD,
    const float* __restrict__ h, const float* __restrict__ bias,
    float* __restrict__ out, int N) {
  __shared__ unsigned spk[AGG_CAP];   // 16 KB
  __shared__ int hist[BNODES];
  __shared__ int rs[BNODES + 1];
  __shared__ int wsum2[4];

  int tid = threadIdx.x;
  int lane = tid & 31;
  int eg = tid >> 5;
  int b = blockIdx.x;
  int start = baseD[b];
  int end = baseD[b + 1];

  float acc[16];
  int degc[16];
#pragma unroll
  for (int t = 0; t < 16; ++t) { acc[t] = 0.f; degc[t] = 0; }

  for (int chunk = start; chunk < end; chunk += AGG_CAP) {
    int cnt = min(end - chunk, AGG_CAP);
    if (tid < BNODES) hist[tid] = 0;
    __syncthreads();

    unsigned mypk[16];
    int myslot[16];
    int nmine = 0;
    for (int i = tid; i < cnt; i += 256) {
      unsigned pk = pairs[chunk + i];
      mypk[nmine] = pk;
      myslot[nmine] = atomicAdd(&hist[pk >> 17], 1);
      ++nmine;
    }
    __syncthreads();

    {
      int v = (tid < BNODES) ? hist[tid] : 0;
      int x = v;
#pragma unroll
      for (int d = 1; d < 64; d <<= 1) {
        int y = __shfl_up(x, d, 64);
        if ((tid & 63) >= d) x += y;
      }
      if ((tid & 63) == 63) wsum2[tid >> 6] = x;
      __syncthreads();
      int off = (tid >= 64 && tid < BNODES) ? wsum2[0] : 0;
      if (tid < BNODES) rs[tid] = off + x - v;
      if (tid == BNODES - 1) rs[BNODES] = off + x;
    }
    __syncthreads();

    for (int i = 0; i < nmine; ++i) {
      unsigned pk = mypk[i];
      spk[rs[pk >> 17] + myslot[i]] = pk;
    }
    __syncthreads();

#pragma unroll 1
    for (int t = 0; t < 16; ++t) {
      int n = eg * 16 + t;
      int a = rs[n], bnd = rs[n + 1];
      degc[t] += bnd - a;
      float s = acc[t];
      int j = a;
      for (; j + 4 <= bnd; j += 4) {
        unsigned p0 = spk[j], p1 = spk[j + 1], p2 = spk[j + 2], p3 = spk[j + 3];
        float f0 = h[(size_t)(p0 & 0x1FFFF) * OUT_F + lane];
        float f1 = h[(size_t)(p1 & 0x1FFFF) * OUT_F + lane];
        float f2 = h[(size_t)(p2 & 0x1FFFF) * OUT_F + lane];
        float f3 = h[(size_t)(p3 & 0x1FFFF) * OUT_F + lane];
        s += f0; s += f1; s += f2; s += f3;
      }
      for (; j < bnd; ++j)
        s += h[(size_t)(spk[j] & 0x1FFFF) * OUT_F + lane];
      acc[t] = s;
    }
    __syncthreads();
  }

  int node0 = b << BSHIFT;
#pragma unroll
  for (int t = 0; t < 16; ++t) {
    int node = node0 + eg * 16 + t;
    if (node < N) {
      float sc = degc[t] > 0 ? rsqrtf((float)degc[t]) : 1.f;
      out[(size_t)node * OUT_F + lane] = fmaxf(fmaf(acc[t], sc, bias[lane]), 0.f);
    }
  }
}

// ---------------- fallback (float-atomic) path ----------------
__global__ __launch_bounds__(256) void degree_kernel(
    const int* __restrict__ src, const int* __restrict__ dst,
    int* __restrict__ cnt_out, int* __restrict__ cnt_in, int E) {
  int i = blockIdx.x * 256 + threadIdx.x;
  if (i < E) {
    atomicAdd(cnt_out + src[i], 1);
    atomicAdd(cnt_in + dst[i], 1);
  }
}

__global__ __launch_bounds__(256) void cnt_to_scale_kernel(
    const int* __restrict__ cnt, float* __restrict__ scale, int N) {
  int i = blockIdx.x * 256 + threadIdx.x;
  if (i < N) {
    int c = cnt[i];
    scale[i] = (c < 1) ? 1.f : rsqrtf((float)c);
  }
}

__global__ __launch_bounds__(256) void aggregate_kernel(
    const int* __restrict__ src, const int* __restrict__ dst,
    const float* __restrict__ h, float* __restrict__ out, int E) {
  int lane = threadIdx.x & 31;
  int e = (blockIdx.x * 256 + threadIdx.x) >> 5;
  if (e >= E) return;
  float v = h[(size_t)src[e] * OUT_F + lane];
  unsafeAtomicAdd(out + (size_t)dst[e] * OUT_F + lane, v);
}

__global__ __launch_bounds__(256) void finalize_kernel(
    float* __restrict__ out, const int* __restrict__ cnt_in,
    const float* __restrict__ bias, int N) {
  int idx = blockIdx.x * 256 + threadIdx.x;
  if (idx >= N * 8) return;
  int n = idx >> 3;
  int o = (idx & 7) * 4;
  float dg = (float)cnt_in[n];
  float s = dg < 1.f ? 1.f : rsqrtf(dg);
  float4 bv = *(const float4*)(bias + o);
  float4 v = ((const float4*)out)[idx];
  v.x = fmaxf(fmaf(v.x, s, bv.x), 0.f);
  v.y = fmaxf(fmaf(v.y, s, bv.y), 0.f);
  v.z = fmaxf(fmaf(v.z, s, bv.z), 0.f);
  v.w = fmaxf(fmaf(v.w, s, bv.w), 0.f);
  ((float4*)out)[idx] = v;
}

extern "C" void kernel_launch(void* const* d_in, const int* in_sizes, int n_in,
                              void* d_out, int out_size, void* d_ws, size_t ws_size,
                              hipStream_t stream) {
  const float* feat = (const float*)d_in[0];
  const int* src = (const int*)d_in[1];
  const int* dst = (const int*)d_in[2];
  const float* weight = (const float*)d_in[3];
  const float* bias = (const float*)d_in[4];
  float* out = (float*)d_out;

  int N = in_sizes[0] / IN_F;
  int E = in_sizes[1];
  int nb = (N + BNODES - 1) >> BSHIFT;
  int npb = (E + PB_EDGES - 1) / PB_EDGES;

  float* h = (float*)d_ws;                                   // N*32 f32
  unsigned* pairs = (unsigned*)(h + (size_t)N * OUT_F);      // E u32
  unsigned char* pairs_s = (unsigned char*)pairs;
  unsigned short* mhistS = (unsigned short*)(pairs + E);     // npb*NBK u16
  unsigned short* mhistD = mhistS + (size_t)npb * NBK;       // npb*NBK u16
  int* baseS = (int*)(mhistD + (size_t)npb * NBK);           // NBK+1
  int* baseD = baseS + NBK + 1;                              // NBK+1
  float* scale_out = (float*)(baseD + NBK + 1);              // N f32

  size_t need = ((size_t)N * OUT_F + (size_t)E + (size_t)N + 2 * (NBK + 1)) * 4 +
                (size_t)npb * NBK * 2 * 2;
  bool fast = (ws_size >= need) && (N <= (1 << 17)) && (nb <= NBK);

  if (fast) {
    hist_kernel<<<npb, 1024, 0, stream>>>(src, dst, mhistS, mhistD, E);
    offset_kernel<<<2, 1024, 0, stream>>>(mhistS, mhistD, baseS, baseD, npb);
    partition_src_kernel<<<npb, 1024, 0, stream>>>(src, mhistS, baseS, pairs_s, E);
    src_count_kernel<<<nb, 256, 0, stream>>>(pairs_s, baseS, scale_out, N);
    gemm_kernel<<<(N + G_ROWS - 1) / G_ROWS, 256, 0, stream>>>(
        feat, weight, scale_out, h, N);
    partition_dst_kernel<<<npb, 1024, 0, stream>>>(src, dst, mhistD, baseD, pairs, E);
    sort_agg_kernel<<<nb, 256, 0, stream>>>(pairs, baseD, h, bias, out, N);
  } else {
    int* cnt_out = (int*)(h + (size_t)N * OUT_F);
    int* cnt_in = cnt_out + N;
    float* scl = (float*)(cnt_in + N);
    hipMemsetAsync(cnt_out, 0, (size_t)2 * N * sizeof(int), stream);
    hipMemsetAsync(out, 0, (size_t)N * OUT_F * sizeof(float), stream);
    degree_kernel<<<(E + 255) / 256, 256, 0, stream>>>(src, dst, cnt_out, cnt_in, E);
    cnt_to_scale_kernel<<<(N + 255) / 256, 256, 0, stream>>>(cnt_out, scl, N);
    gemm_kernel<<<(N + G_ROWS - 1) / G_ROWS, 256, 0, stream>>>(feat, weight, scl, h, N);
    aggregate_kernel<<<(E + 7) / 8, 256, 0, stream>>>(src, dst, h, out, E);
    finalize_kernel<<<(N * 8 + 255) / 256, 256, 0, stream>>>(out, cnt_in, bias, N);
  }
}